// Round 4
// baseline (250.374 us; speedup 1.0000x reference)
//
#include <hip/hip_runtime.h>

typedef __attribute__((ext_vector_type(8))) __bf16 bf16x8;
typedef __attribute__((ext_vector_type(8))) unsigned short us8;
typedef __attribute__((ext_vector_type(4))) float f32x4;

#define B_TOTAL 131072

__device__ __forceinline__ unsigned short f2bf(float f) {
  union { float f; unsigned int u; } c; c.f = f;
  unsigned int u = c.u;
  u += 0x7fffu + ((u >> 16) & 1u);   // RNE
  return (unsigned short)(u >> 16);
}
__device__ __forceinline__ bf16x8 as_bf(us8 v) {
  union { us8 u; bf16x8 b; } c; c.u = v; return c.b;
}
__device__ __forceinline__ float fast_tanh(float x) {
  float t = __expf(2.0f * x);        // inf-safe: 1-2/inf=1, 1-2/1=-1
  return 1.0f - 2.0f / (t + 1.0f);
}

// ---------------- prep: pre-arrange B-fragments (bf16) into ws -----------------
// rwfrag[s][kh][lane][e] = rw[h=(lane>>4)*8+e][k=kh*16+(lane&15)][s]
// qwfrag[s][kh][lane<16][e] = qw[i=e][h=kh*16+lane][s]
// dgfrag[kh][lane][e] = (h==k) ? bf16(1 - 0.1/tau[k]) : 0
__global__ void shq_prep(const float* __restrict__ qw, const float* __restrict__ rw,
                         const float* __restrict__ tau,
                         unsigned short* __restrict__ rwfrag,
                         unsigned short* __restrict__ qwfrag,
                         unsigned short* __restrict__ dgfrag) {
  int g = blockIdx.x * 256 + threadIdx.x;
  if (g < 2048) {
    int s = g >> 7, kh = (g >> 6) & 1, ln = g & 63;
    int k = kh * 16 + (ln & 15), h0 = (ln >> 4) * 8;
    us8 v;
#pragma unroll
    for (int e = 0; e < 8; ++e) v[e] = f2bf(rw[((h0 + e) * 32 + k) * 16 + s]);
    *(us8*)(rwfrag + g * 8) = v;
  } else if (g < 2560) {
    int j = g - 2048;
    int s = j >> 5, kh = (j >> 4) & 1, ln = j & 15;
    int hc = kh * 16 + ln;
    us8 v;
#pragma unroll
    for (int e = 0; e < 8; ++e) v[e] = f2bf(qw[(e * 32 + hc) * 16 + s]);
    *(us8*)(qwfrag + j * 8) = v;
  } else if (g < 2688) {
    int j = g - 2560;
    int kh = (j >> 6) & 1, ln = j & 63;
    int k = kh * 16 + (ln & 15), h0 = (ln >> 4) * 8;
    unsigned short ab = f2bf(1.0f - 0.1f / tau[k]);
    us8 v;
#pragma unroll
    for (int e = 0; e < 8; ++e) v[e] = (h0 + e == k) ? ab : (unsigned short)0;
    *(us8*)(dgfrag + j * 8) = v;
  }
}

// ------------- main kernel: fully wave-local, no LDS, no barriers -------------
// Each wave owns 16 batch rows and ALL 16 s-slices.
// Lane roles:  phase 1 (A-side): bi=lane&15 -> batch row, g=lane>>4 -> h-octet.
//              after MFMA (C-side): lane holds (b = g*4+r, k = kh*16+bi, all s).
__global__ __launch_bounds__(256, 2) void shq_main(
    const float* __restrict__ x, const float* __restrict__ hq_g,
    const float* __restrict__ syn, const float* __restrict__ corr,
    const unsigned short* __restrict__ rwfrag,
    const unsigned short* __restrict__ qwfrag,
    const unsigned short* __restrict__ dgfrag,
    float* __restrict__ out) {
  const int tid = threadIdx.x;
  const int lane = tid & 63;
  const size_t b0 = ((size_t)blockIdx.x * 4 + (tid >> 6)) * 16;
  const int g = lane >> 4;
  const int bi = lane & 15;

  us8 z8 = {0, 0, 0, 0, 0, 0, 0, 0};

  // ---- phase 1: load 8 h-rows (all s) for batch bi; syndrome; correct; frags ----
  f32x4 hq[8][4];                         // [h-row e][s-quad]
  {
    const float* hb = hq_g + ((b0 + bi) * 32 + (size_t)g * 8) * 16;
#pragma unroll
    for (int e = 0; e < 8; ++e)
#pragma unroll
      for (int c = 0; c < 4; ++c)
        hq[e][c] = *(const f32x4*)(hb + e * 16 + c * 4);
  }
  float sd[8][4];                         // syndromes (from RAW h_quantum)
#pragma unroll
  for (int e = 0; e < 8; ++e)
#pragma unroll
    for (int c = 0; c < 4; ++c) {
      float a = 0.f;
#pragma unroll
      for (int s = 0; s < 16; ++s) a = fmaf(hq[e][s >> 2][s & 3], syn[c * 16 + s], a);
      sd[e][c] = (fabsf(a) > 0.01f) ? a : 0.f;
    }
  bf16x8 frag[16];                        // A-frag per s: elem e = h-row
#pragma unroll
  for (int s = 0; s < 16; ++s) {
#pragma unroll
    for (int e = 0; e < 8; ++e) {
      float cs = fmaf(sd[e][0], corr[s],
                 fmaf(sd[e][1], corr[16 + s],
                 fmaf(sd[e][2], corr[32 + s], sd[e][3] * corr[48 + s])));
      frag[s][e] = (__bf16)(hq[e][s >> 2][s & 3] - cs);
    }
  }

  // x A-frag (K=i lives only in octet g==0)
  bf16x8 xf = as_bf(z8);
  if (g == 0) {
    const float* xb = x + (b0 + bi) * 8;
    f32x4 a = *(const f32x4*)xb, bv = *(const f32x4*)(xb + 4);
#pragma unroll
    for (int e = 0; e < 4; ++e) { xf[e] = (__bf16)a[e]; xf[e + 4] = (__bf16)bv[e]; }
  }
  bf16x8 dgf0 = as_bf(*(const us8*)(dgfrag + lane * 8));
  bf16x8 dgf1 = as_bf(*(const us8*)(dgfrag + (64 + lane) * 8));

  // ---- phase 2: 3-MFMA chain per (s, kh); nq stays in registers ----
  f32x4 nq[2][16];
  const f32x4 zro = {0.f, 0.f, 0.f, 0.f};
#pragma unroll
  for (int s = 0; s < 16; ++s) {
#pragma unroll
    for (int kh = 0; kh < 2; ++kh) {
      bf16x8 rwv = as_bf(*(const us8*)(rwfrag + ((s * 2 + kh) * 64 + lane) * 8));
      bf16x8 qwv = (g == 0) ? as_bf(*(const us8*)(qwfrag + ((s * 2 + kh) * 16 + bi) * 8))
                            : as_bf(z8);
      f32x4 acc = __builtin_amdgcn_mfma_f32_16x16x32_bf16(xf, qwv, zro, 0, 0, 0);
      acc = __builtin_amdgcn_mfma_f32_16x16x32_bf16(frag[s], rwv, acc, 0, 0, 0);
      f32x4 na;
#pragma unroll
      for (int r = 0; r < 4; ++r) na[r] = 0.1f * fast_tanh(acc[r]);
      nq[kh][s] = __builtin_amdgcn_mfma_f32_16x16x32_bf16(frag[s], dgf0 /*patched below*/, na, 0, 0, 0);
      if (kh) nq[1][s] = __builtin_amdgcn_mfma_f32_16x16x32_bf16(frag[s], dgf1, na, 0, 0, 0);
      else    nq[0][s] = __builtin_amdgcn_mfma_f32_16x16x32_bf16(frag[s], dgf0, na, 0, 0, 0);
    }
  }

  // ---- phase 3a: stable + norm reductions (16-lane butterfly per s) ----
  float ssqk[4], sabk[4];
#pragma unroll
  for (int s = 0; s < 16; ++s) {
    float ssq[4], sab[4];
#pragma unroll
    for (int r = 0; r < 4; ++r) {
      float c0 = nq[0][s][r], c1 = nq[1][s][r];
      float nb0 = ((s > 0) ? nq[0][s - 1][r] : 0.f) + ((s < 15) ? nq[0][s + 1][r] : 0.f);
      float nb1 = ((s > 0) ? nq[1][s - 1][r] : 0.f) + ((s < 15) ? nq[1][s + 1][r] : 0.f);
      float st0 = fmaf(0.04f * c0, nb0, c0);
      float st1 = fmaf(0.04f * c1, nb1, c1);
      ssq[r] = fmaf(st0, st0, st1 * st1);
      sab[r] = fabsf(st0) + fabsf(st1);
    }
#pragma unroll
    for (int m = 1; m < 16; m <<= 1)
#pragma unroll
      for (int r = 0; r < 4; ++r) {
        ssq[r] += __shfl_xor(ssq[r], m);
        sab[r] += __shfl_xor(sab[r], m);
      }
    if (bi == s) {                        // keeper lane holds (b=g*4+r, s=bi)
#pragma unroll
      for (int r = 0; r < 4; ++r) { ssqk[r] = ssq[r]; sabk[r] = sab[r]; }
    }
  }
  float invk[4], puk[4], prk[4];
#pragma unroll
  for (int r = 0; r < 4; ++r) {
    float inv = __fdividef(1.f, sqrtf(ssqk[r]) + 1e-8f);
    invk[r] = inv;
    puk[r] = __fdividef(sabk[r] * inv, fmaf(ssqk[r] * inv, inv, 1e-6f));
  }
  {
    float ps[4] = {puk[0], puk[1], puk[2], puk[3]};
#pragma unroll
    for (int m = 1; m < 16; m <<= 1)
#pragma unroll
      for (int r = 0; r < 4; ++r) ps[r] += __shfl_xor(ps[r], m);
#pragma unroll
    for (int r = 0; r < 4; ++r) prk[r] = __fdividef(puk[r], ps[r]);
  }

  // ---- phase 3b: q_norm + output; broadcast inv/prob from keeper lanes ----
  float* qbase = out + 4194304;
#pragma unroll
  for (int r = 0; r < 4; ++r) {
    const size_t bb = b0 + g * 4 + r;
    float* qp0 = qbase + (bb * 32 + bi) * 16;
    float* qp1 = qbase + (bb * 32 + 16 + bi) * 16;
    float oa0 = 0.f, oa1 = 0.f;
    f32x4 q0v, q1v;
#pragma unroll
    for (int s = 0; s < 16; ++s) {
      float inv = __shfl(invk[r], s, 16);
      float pr  = __shfl(prk[r], s, 16);
      float c0 = nq[0][s][r], c1 = nq[1][s][r];
      float nb0 = ((s > 0) ? nq[0][s - 1][r] : 0.f) + ((s < 15) ? nq[0][s + 1][r] : 0.f);
      float nb1 = ((s > 0) ? nq[1][s - 1][r] : 0.f) + ((s < 15) ? nq[1][s + 1][r] : 0.f);
      float q0 = fmaf(0.04f * c0, nb0, c0) * inv;
      float q1 = fmaf(0.04f * c1, nb1, c1) * inv;
      q0v[s & 3] = q0; q1v[s & 3] = q1;
      oa0 = fmaf(q0, pr, oa0);
      oa1 = fmaf(q1, pr, oa1);
      if ((s & 3) == 3) {
        *(f32x4*)(qp0 + (s - 3)) = q0v;
        *(f32x4*)(qp1 + (s - 3)) = q1v;
      }
    }
    out[bb * 32 + bi] = oa0;
    out[bb * 32 + 16 + bi] = oa1;
  }
}

extern "C" void kernel_launch(void* const* d_in, const int* in_sizes, int n_in,
                              void* d_out, int out_size, void* d_ws, size_t ws_size,
                              hipStream_t stream) {
  const float* x    = (const float*)d_in[0];
  const float* hq   = (const float*)d_in[1];
  const float* qw   = (const float*)d_in[2];
  const float* rw   = (const float*)d_in[3];
  const float* tau  = (const float*)d_in[4];
  const float* syn  = (const float*)d_in[5];
  const float* corr = (const float*)d_in[6];
  unsigned short* ws = (unsigned short*)d_ws;
  unsigned short* rwfrag = ws;            // 16384 shorts
  unsigned short* qwfrag = ws + 16384;    // 4096 shorts
  unsigned short* dgfrag = ws + 20480;    // 1024 shorts
  shq_prep<<<11, 256, 0, stream>>>(qw, rw, tau, rwfrag, qwfrag, dgfrag);
  shq_main<<<B_TOTAL / 64, 256, 0, stream>>>(x, hq, syn, corr, rwfrag, qwfrag, dgfrag, (float*)d_out);
}

// Round 8
// 154.854 us; speedup vs baseline: 1.6168x; 1.6168x over previous
//
#include <hip/hip_runtime.h>

typedef __attribute__((ext_vector_type(8))) __bf16 bf16x8;
typedef __attribute__((ext_vector_type(8))) unsigned short us8;
typedef __attribute__((ext_vector_type(4))) float f32x4;

#define NB 16
#define B_TOTAL 131072
#define SST 36            // nq s-stride (floats)
#define BST 580           // nq b-stride (floats) = 16*36+4

__device__ __forceinline__ unsigned short f2bf(float f) {
  union { float f; unsigned int u; } c; c.f = f;
  unsigned int u = c.u;
  u += 0x7fffu + ((u >> 16) & 1u);   // RNE
  return (unsigned short)(u >> 16);
}
__device__ __forceinline__ bf16x8 as_bf(us8 v) {
  union { us8 u; bf16x8 b; } c; c.u = v; return c.b;
}
__device__ __forceinline__ float fast_tanh(float x) {
  float t = __expf(2.0f * x);        // inf-safe: 1-2/inf=1, 1-2/1=-1
  return 1.0f - 2.0f / (t + 1.0f);
}

// ---------------- prep: pre-arrange B-fragments (bf16) into ws -----------------
__global__ void shq_prep(const float* __restrict__ qw, const float* __restrict__ rw,
                         const float* __restrict__ tau,
                         unsigned short* __restrict__ rwfrag,
                         unsigned short* __restrict__ qwfrag,
                         unsigned short* __restrict__ dgfrag) {
  int g = blockIdx.x * 256 + threadIdx.x;
  if (g < 2048) {                       // 16 s * 2 kh * 64 lanes
    int s = g >> 7, kh = (g >> 6) & 1, ln = g & 63;
    int k = kh * 16 + (ln & 15), h0 = (ln >> 4) * 8;
    us8 v;
#pragma unroll
    for (int e = 0; e < 8; ++e) v[e] = f2bf(rw[((h0 + e) * 32 + k) * 16 + s]);
    *(us8*)(rwfrag + g * 8) = v;
  } else if (g < 2560) {                // 16 s * 2 kh * 16 lanes
    int j = g - 2048;
    int s = j >> 5, kh = (j >> 4) & 1, ln = j & 15;
    int hc = kh * 16 + ln;
    us8 v;
#pragma unroll
    for (int e = 0; e < 8; ++e) v[e] = f2bf(qw[(e * 32 + hc) * 16 + s]);
    *(us8*)(qwfrag + j * 8) = v;
  } else if (g < 2688) {                // 2 kh * 64 lanes
    int j = g - 2560;
    int kh = (j >> 6) & 1, ln = j & 63;
    int k = kh * 16 + (ln & 15), h0 = (ln >> 4) * 8;
    unsigned short ab = f2bf(1.0f - 0.1f / tau[k]);
    us8 v;
#pragma unroll
    for (int e = 0; e < 8; ++e) v[e] = (h0 + e == k) ? ab : (unsigned short)0;
    *(us8*)(dgfrag + j * 8) = v;
  }
}

// ---------------- main kernel: 512 threads = 16 batch rows ----------------
__global__ __launch_bounds__(512, 2) void shq_main(
    const float* __restrict__ x, const float* __restrict__ hq_g,
    const float* __restrict__ syn, const float* __restrict__ corr,
    const unsigned short* __restrict__ rwfrag,
    const unsigned short* __restrict__ qwfrag,
    const unsigned short* __restrict__ dgfrag,
    float* __restrict__ out) {
  // Time-multiplexed buffer:
  //   [barA, barB): hqT bf16 [s][b][h], strides s:640, b:40 shorts (20.5 KB)
  //   [barB, end):  nq   f32 [b][s][h], strides b:BST, s:SST floats (37.1 KB)
  __shared__ float smem[16 * BST];
  __shared__ float2 lds_pi[NB * 16];   // (prob, inv_norm) per (b,s)
  unsigned short* hqT = (unsigned short*)smem;

  const int tid = threadIdx.x;
  const int b0 = blockIdx.x * NB;
  const int lane = tid & 63;
  const int w = tid >> 6;     // wave id: owns s = 2w, 2w+1

  us8 z8 = {0, 0, 0, 0, 0, 0, 0, 0};

  // ---- prologue: x row (bf16 A-frag) ----
  us8 xu = z8;
  if (lane < 16) {
    const float* xb = x + (size_t)(b0 + lane) * 8;
    f32x4 a = *(const f32x4*)xb, b = *(const f32x4*)(xb + 4);
    xu[0] = f2bf(a[0]); xu[1] = f2bf(a[1]); xu[2] = f2bf(a[2]); xu[3] = f2bf(a[3]);
    xu[4] = f2bf(b[0]); xu[5] = f2bf(b[1]); xu[6] = f2bf(b[2]); xu[7] = f2bf(b[3]);
  }

  // ---- phase 1: thread=(bl,h): syndrome -> mask -> correction -> hqT ----
  {
    const int bl = tid >> 5, hh = tid & 31;
    const float* hb = hq_g + (((size_t)(b0 + bl) * 32) + hh) * 16;
    f32x4 h0 = *(const f32x4*)(hb), h1 = *(const f32x4*)(hb + 4);
    f32x4 h2 = *(const f32x4*)(hb + 8), h3 = *(const f32x4*)(hb + 12);
    float hrow[16];
#pragma unroll
    for (int q = 0; q < 4; ++q) {
      hrow[0 + q] = h0[q]; hrow[4 + q] = h1[q]; hrow[8 + q] = h2[q]; hrow[12 + q] = h3[q];
    }
    float sd[4];
#pragma unroll
    for (int c = 0; c < 4; ++c) {
      float a = 0.f;
#pragma unroll
      for (int s = 0; s < 16; ++s) a = fmaf(hrow[s], syn[c * 16 + s], a);
      sd[c] = (fabsf(a) > 0.01f) ? a : 0.f;
    }
#pragma unroll
    for (int s = 0; s < 16; ++s) {
      float cs = sd[0] * corr[s] + sd[1] * corr[16 + s] + sd[2] * corr[32 + s] + sd[3] * corr[48 + s];
      hqT[s * 640 + bl * 40 + hh] = f2bf(hrow[s] - cs);
    }
  }
  __syncthreads();   // A: hqT ready

  // ---- phase 2a: pull A-frags (hq) out of hqT before it is clobbered ----
  us8 hq_u[2];
#pragma unroll
  for (int sl = 0; sl < 2; ++sl)
    hq_u[sl] = *(const us8*)&hqT[(2 * w + sl) * 640 + (lane & 15) * 40 + (lane >> 4) * 8];
  us8 dg0 = *(const us8*)(dgfrag + lane * 8);
  us8 dg1 = *(const us8*)(dgfrag + (64 + lane) * 8);
  __syncthreads();   // B: hqT dead, nq region free

  // ---- phase 2b: MFMA rec+inp+decay per (s, khalf); write new_q f32 ----
  {
    f32x4 zro = {0.f, 0.f, 0.f, 0.f};
#pragma unroll
    for (int sl = 0; sl < 2; ++sl) {
      int s = 2 * w + sl;
      us8 rw0 = *(const us8*)(rwfrag + ((s * 2 + 0) * 64 + lane) * 8);
      us8 rw1 = *(const us8*)(rwfrag + ((s * 2 + 1) * 64 + lane) * 8);
      us8 qw0 = (lane < 16) ? *(const us8*)(qwfrag + ((s * 2 + 0) * 16 + lane) * 8) : z8;
      us8 qw1 = (lane < 16) ? *(const us8*)(qwfrag + ((s * 2 + 1) * 16 + lane) * 8) : z8;
      bf16x8 hqf = as_bf(hq_u[sl]);
#pragma unroll
      for (int kh = 0; kh < 2; ++kh) {
        f32x4 acc = __builtin_amdgcn_mfma_f32_16x16x32_bf16(as_bf(xu), as_bf(kh ? qw1 : qw0), zro, 0, 0, 0);
        acc = __builtin_amdgcn_mfma_f32_16x16x32_bf16(hqf, as_bf(kh ? rw1 : rw0), acc, 0, 0, 0);
        f32x4 na;
#pragma unroll
        for (int r = 0; r < 4; ++r) na[r] = 0.1f * fast_tanh(acc[r]);
        na = __builtin_amdgcn_mfma_f32_16x16x32_bf16(hqf, as_bf(kh ? dg1 : dg0), na, 0, 0, 0);
        int k = kh * 16 + (lane & 15);
#pragma unroll
        for (int r = 0; r < 4; ++r) {
          int br = (lane >> 4) * 4 + r;
          smem[br * BST + s * SST + k] = na[r];
        }
      }
    }
  }
  __syncthreads();   // C: nq ready

  // ---- phase 3a: thread=(b,s,half): stream stable, reduce norms, write pi ----
  {
    int b3 = tid >> 5, idx = tid & 31;
    int s3 = idx >> 1, half = idx & 1;
    int base = b3 * BST + s3 * SST + half * 16;
    float ssq = 0.f, sab = 0.f;
    f32x4 zv = {0.f, 0.f, 0.f, 0.f};
#pragma unroll
    for (int q = 0; q < 4; ++q) {
      f32x4 c0 = *(const f32x4*)&smem[base + 4 * q];
      f32x4 cm = (s3 > 0)  ? *(const f32x4*)&smem[base - SST + 4 * q] : zv;
      f32x4 cp = (s3 < 15) ? *(const f32x4*)&smem[base + SST + 4 * q] : zv;
#pragma unroll
      for (int e = 0; e < 4; ++e) {
        float st = fmaf(0.04f * c0[e], cm[e] + cp[e], c0[e]);
        ssq = fmaf(st, st, ssq);
        sab += fabsf(st);
      }
    }
    ssq += __shfl_xor(ssq, 1);
    sab += __shfl_xor(sab, 1);
    float inv = __fdividef(1.0f, sqrtf(ssq) + 1e-8f);
    float energy = ssq * inv * inv;
    float mag = sab * inv;
    float pu = __fdividef(mag, energy + 1e-6f);
    float psum = pu;
#pragma unroll
    for (int m = 2; m < 32; m <<= 1) psum += __shfl_xor(psum, m);
    if (half == 0) {
      float2 pv = {__fdividef(pu, psum), inv};
      lds_pi[b3 * 16 + s3] = pv;
    }
  }
  __syncthreads();   // D: pi ready (nq untouched)

  // ---- phase 3b: thread=(b,h): streaming stable column, q_norm + output ----
  {
    const int b3 = tid >> 5, h3 = tid & 31;
    const float* colp = smem + b3 * BST + h3;
    float* qp = out + 4194304 + (((size_t)(b0 + b3) * 32) + h3) * 16;
    float prev = 0.f;
    float cur = colp[0];
    float oacc = 0.f;
    f32x4 qbuf;
#pragma unroll
    for (int s = 0; s < 16; ++s) {
      float nxt = (s < 15) ? colp[(s + 1) * SST] : 0.f;
      float st = fmaf(0.04f * cur, prev + nxt, cur);
      float2 pv = lds_pi[b3 * 16 + s];
      float q = st * pv.y;
      qbuf[s & 3] = q;
      oacc = fmaf(q, pv.x, oacc);
      if ((s & 3) == 3) *(f32x4*)(qp + (s - 3)) = qbuf;
      prev = cur; cur = nxt;
    }
    out[(size_t)(b0 + b3) * 32 + h3] = oacc;
  }
}

extern "C" void kernel_launch(void* const* d_in, const int* in_sizes, int n_in,
                              void* d_out, int out_size, void* d_ws, size_t ws_size,
                              hipStream_t stream) {
  const float* x    = (const float*)d_in[0];
  const float* hq   = (const float*)d_in[1];
  const float* qw   = (const float*)d_in[2];
  const float* rw   = (const float*)d_in[3];
  const float* tau  = (const float*)d_in[4];
  const float* syn  = (const float*)d_in[5];
  const float* corr = (const float*)d_in[6];
  unsigned short* ws = (unsigned short*)d_ws;
  unsigned short* rwfrag = ws;            // 16384 shorts
  unsigned short* qwfrag = ws + 16384;    // 4096 shorts
  unsigned short* dgfrag = ws + 20480;    // 1024 shorts
  shq_prep<<<11, 256, 0, stream>>>(qw, rw, tau, rwfrag, qwfrag, dgfrag);
  shq_main<<<B_TOTAL / NB, 512, 0, stream>>>(x, hq, syn, corr, rwfrag, qwfrag, dgfrag, (float*)d_out);
}

// Round 10
// 153.050 us; speedup vs baseline: 1.6359x; 1.0118x over previous
//
#include <hip/hip_runtime.h>

typedef __attribute__((ext_vector_type(8))) __bf16 bf16x8;
typedef __attribute__((ext_vector_type(8))) unsigned short us8;
typedef __attribute__((ext_vector_type(4))) float f32x4;

#define NB 16
#define B_TOTAL 131072
#define SST 36            // nq s-stride (floats)
#define BST 580           // nq b-stride (floats) = 16*36+4

__device__ __forceinline__ unsigned short f2bf(float f) {
  union { float f; unsigned int u; } c; c.f = f;
  unsigned int u = c.u;
  u += 0x7fffu + ((u >> 16) & 1u);   // RNE
  return (unsigned short)(u >> 16);
}
__device__ __forceinline__ bf16x8 as_bf(us8 v) {
  union { us8 u; bf16x8 b; } c; c.u = v; return c.b;
}
// 0.1 * tanh(x), fast: 0.1 - 0.2/(e^{2x}+1); rcp-based divide (err ~2^-21)
// inf-safe: x large -> 0.1 - 0 = 0.1 ; x very negative -> 0.1 - 0.2 = -0.1
__device__ __forceinline__ float tanh01(float x) {
  float t = __expf(2.0f * x);
  return 0.1f - __fdividef(0.2f, t + 1.0f);
}

// ---------------- prep: pre-arrange B-fragments (bf16) into ws -----------------
__global__ void shq_prep(const float* __restrict__ qw, const float* __restrict__ rw,
                         const float* __restrict__ tau,
                         unsigned short* __restrict__ rwfrag,
                         unsigned short* __restrict__ qwfrag,
                         unsigned short* __restrict__ dgfrag) {
  int g = blockIdx.x * 256 + threadIdx.x;
  if (g < 2048) {                       // 16 s * 2 kh * 64 lanes
    int s = g >> 7, kh = (g >> 6) & 1, ln = g & 63;
    int k = kh * 16 + (ln & 15), h0 = (ln >> 4) * 8;
    us8 v;
#pragma unroll
    for (int e = 0; e < 8; ++e) v[e] = f2bf(rw[((h0 + e) * 32 + k) * 16 + s]);
    *(us8*)(rwfrag + g * 8) = v;
  } else if (g < 2560) {                // 16 s * 2 kh * 16 lanes
    int j = g - 2048;
    int s = j >> 5, kh = (j >> 4) & 1, ln = j & 15;
    int hc = kh * 16 + ln;
    us8 v;
#pragma unroll
    for (int e = 0; e < 8; ++e) v[e] = f2bf(qw[(e * 32 + hc) * 16 + s]);
    *(us8*)(qwfrag + j * 8) = v;
  } else if (g < 2688) {                // 2 kh * 64 lanes
    int j = g - 2560;
    int kh = (j >> 6) & 1, ln = j & 63;
    int k = kh * 16 + (ln & 15), h0 = (ln >> 4) * 8;
    unsigned short ab = f2bf(1.0f - 0.1f / tau[k]);
    us8 v;
#pragma unroll
    for (int e = 0; e < 8; ++e) v[e] = (h0 + e == k) ? ab : (unsigned short)0;
    *(us8*)(dgfrag + j * 8) = v;
  }
}

// ---------------- main kernel: 512 threads = 16 batch rows ----------------
__global__ __launch_bounds__(512, 2) void shq_main(
    const float* __restrict__ x, const float* __restrict__ hq_g,
    const float* __restrict__ syn, const float* __restrict__ corr,
    const unsigned short* __restrict__ rwfrag,
    const unsigned short* __restrict__ qwfrag,
    const unsigned short* __restrict__ dgfrag,
    float* __restrict__ out) {
  // Time-multiplexed buffer:
  //   [barA, barB): hqT bf16 [s][b][h], strides s:640, b:40 shorts (20.5 KB)
  //   [barB, end):  nq   f32 [b][s][h], strides b:BST, s:SST floats (37.1 KB)
  __shared__ float smem[16 * BST];
  __shared__ float2 lds_pi[NB * 16];   // (prob, inv_norm) per (b,s)
  unsigned short* hqT = (unsigned short*)smem;

  const int tid = threadIdx.x;
  const int b0 = blockIdx.x * NB;
  const int lane = tid & 63;
  const int w = tid >> 6;     // wave id: owns s = 2w, 2w+1

  us8 z8 = {0, 0, 0, 0, 0, 0, 0, 0};

  // ---- prologue: x row (bf16 A-frag) ----
  us8 xu = z8;
  if (lane < 16) {
    const float* xb = x + (size_t)(b0 + lane) * 8;
    f32x4 a = *(const f32x4*)xb, b = *(const f32x4*)(xb + 4);
    xu[0] = f2bf(a[0]); xu[1] = f2bf(a[1]); xu[2] = f2bf(a[2]); xu[3] = f2bf(a[3]);
    xu[4] = f2bf(b[0]); xu[5] = f2bf(b[1]); xu[6] = f2bf(b[2]); xu[7] = f2bf(b[3]);
  }

  // ---- phase 1: thread=(bl,h): syndrome -> mask -> correction -> hqT ----
  {
    const int bl = tid >> 5, hh = tid & 31;
    const float* hb = hq_g + (((size_t)(b0 + bl) * 32) + hh) * 16;
    f32x4 h0 = *(const f32x4*)(hb), h1 = *(const f32x4*)(hb + 4);
    f32x4 h2 = *(const f32x4*)(hb + 8), h3 = *(const f32x4*)(hb + 12);
    float hrow[16];
#pragma unroll
    for (int q = 0; q < 4; ++q) {
      hrow[0 + q] = h0[q]; hrow[4 + q] = h1[q]; hrow[8 + q] = h2[q]; hrow[12 + q] = h3[q];
    }
    float sd[4];
#pragma unroll
    for (int c = 0; c < 4; ++c) {
      float a = 0.f;
#pragma unroll
      for (int s = 0; s < 16; ++s) a = fmaf(hrow[s], syn[c * 16 + s], a);
      sd[c] = (fabsf(a) > 0.01f) ? a : 0.f;
    }
#pragma unroll
    for (int s = 0; s < 16; ++s) {
      float cs = sd[0] * corr[s] + sd[1] * corr[16 + s] + sd[2] * corr[32 + s] + sd[3] * corr[48 + s];
      hqT[s * 640 + bl * 40 + hh] = f2bf(hrow[s] - cs);
    }
  }
  __syncthreads();   // A: hqT ready

  // ---- phase 2a: pull A-frags (hq) out of hqT before it is clobbered ----
  us8 hq_u[2];
#pragma unroll
  for (int sl = 0; sl < 2; ++sl)
    hq_u[sl] = *(const us8*)&hqT[(2 * w + sl) * 640 + (lane & 15) * 40 + (lane >> 4) * 8];
  us8 dg0 = *(const us8*)(dgfrag + lane * 8);
  us8 dg1 = *(const us8*)(dgfrag + (64 + lane) * 8);
  __syncthreads();   // B: hqT dead, nq region free

  // ---- phase 2b: MFMA rec+inp+decay per (s, khalf); write new_q f32 ----
  {
    f32x4 zro = {0.f, 0.f, 0.f, 0.f};
#pragma unroll
    for (int sl = 0; sl < 2; ++sl) {
      int s = 2 * w + sl;
      us8 rw0 = *(const us8*)(rwfrag + ((s * 2 + 0) * 64 + lane) * 8);
      us8 rw1 = *(const us8*)(rwfrag + ((s * 2 + 1) * 64 + lane) * 8);
      us8 qw0 = (lane < 16) ? *(const us8*)(qwfrag + ((s * 2 + 0) * 16 + lane) * 8) : z8;
      us8 qw1 = (lane < 16) ? *(const us8*)(qwfrag + ((s * 2 + 1) * 16 + lane) * 8) : z8;
      bf16x8 hqf = as_bf(hq_u[sl]);
#pragma unroll
      for (int kh = 0; kh < 2; ++kh) {
        f32x4 acc = __builtin_amdgcn_mfma_f32_16x16x32_bf16(as_bf(xu), as_bf(kh ? qw1 : qw0), zro, 0, 0, 0);
        acc = __builtin_amdgcn_mfma_f32_16x16x32_bf16(hqf, as_bf(kh ? rw1 : rw0), acc, 0, 0, 0);
        f32x4 na;
#pragma unroll
        for (int r = 0; r < 4; ++r) na[r] = tanh01(acc[r]);
        na = __builtin_amdgcn_mfma_f32_16x16x32_bf16(hqf, as_bf(kh ? dg1 : dg0), na, 0, 0, 0);
        int k = kh * 16 + (lane & 15);
#pragma unroll
        for (int r = 0; r < 4; ++r) {
          int br = (lane >> 4) * 4 + r;
          smem[br * BST + s * SST + k] = na[r];
        }
      }
    }
  }
  __syncthreads();   // C: nq ready

  // ---- phase 3a: thread=(b,s,half): stream stable, reduce norms, write pi ----
  {
    int b3 = tid >> 5, idx = tid & 31;
    int s3 = idx >> 1, half = idx & 1;
    int base = b3 * BST + s3 * SST + half * 16;
    float ssq = 0.f, sab = 0.f;
    f32x4 zv = {0.f, 0.f, 0.f, 0.f};
#pragma unroll
    for (int q = 0; q < 4; ++q) {
      f32x4 c0 = *(const f32x4*)&smem[base + 4 * q];
      f32x4 cm = (s3 > 0)  ? *(const f32x4*)&smem[base - SST + 4 * q] : zv;
      f32x4 cp = (s3 < 15) ? *(const f32x4*)&smem[base + SST + 4 * q] : zv;
#pragma unroll
      for (int e = 0; e < 4; ++e) {
        float st = fmaf(0.04f * c0[e], cm[e] + cp[e], c0[e]);
        ssq = fmaf(st, st, ssq);
        sab += fabsf(st);
      }
    }
    ssq += __shfl_xor(ssq, 1);
    sab += __shfl_xor(sab, 1);
    float inv = __fdividef(1.0f, sqrtf(ssq) + 1e-8f);
    float energy = ssq * inv * inv;
    float mag = sab * inv;
    float pu = __fdividef(mag, energy + 1e-6f);
    float psum = pu;
#pragma unroll
    for (int m = 2; m < 32; m <<= 1) psum += __shfl_xor(psum, m);
    if (half == 0) {
      float2 pv = {__fdividef(pu, psum), inv};
      lds_pi[b3 * 16 + s3] = pv;
    }
  }
  __syncthreads();   // D: pi ready (nq untouched)

  // ---- phase 3b: thread=(b,h): streaming stable column, q_norm + output ----
  {
    const int b3 = tid >> 5, h3 = tid & 31;
    const float* colp = smem + b3 * BST + h3;
    float* qp = out + 4194304 + (((size_t)(b0 + b3) * 32) + h3) * 16;
    float prev = 0.f;
    float cur = colp[0];
    float oacc = 0.f;
    f32x4 qbuf;
#pragma unroll
    for (int s = 0; s < 16; ++s) {
      float nxt = (s < 15) ? colp[(s + 1) * SST] : 0.f;
      float st = fmaf(0.04f * cur, prev + nxt, cur);
      float2 pv = lds_pi[b3 * 16 + s];
      float q = st * pv.y;
      qbuf[s & 3] = q;
      oacc = fmaf(q, pv.x, oacc);
      if ((s & 3) == 3) *(f32x4*)(qp + (s - 3)) = qbuf;
      prev = cur; cur = nxt;
    }
    out[(size_t)(b0 + b3) * 32 + h3] = oacc;
  }
}

extern "C" void kernel_launch(void* const* d_in, const int* in_sizes, int n_in,
                              void* d_out, int out_size, void* d_ws, size_t ws_size,
                              hipStream_t stream) {
  const float* x    = (const float*)d_in[0];
  const float* hq   = (const float*)d_in[1];
  const float* qw   = (const float*)d_in[2];
  const float* rw   = (const float*)d_in[3];
  const float* tau  = (const float*)d_in[4];
  const float* syn  = (const float*)d_in[5];
  const float* corr = (const float*)d_in[6];
  unsigned short* ws = (unsigned short*)d_ws;
  unsigned short* rwfrag = ws;            // 16384 shorts
  unsigned short* qwfrag = ws + 16384;    // 4096 shorts
  unsigned short* dgfrag = ws + 20480;    // 1024 shorts
  shq_prep<<<11, 256, 0, stream>>>(qw, rw, tau, rwfrag, qwfrag, dgfrag);
  shq_main<<<B_TOTAL / NB, 512, 0, stream>>>(x, hq, syn, corr, rwfrag, qwfrag, dgfrag, (float*)d_out);
}